// Round 4
// baseline (211.712 us; speedup 1.0000x reference)
//
#include <hip/hip_runtime.h>
#include <hip/hip_bf16.h>

// SegmentLinear: y = sum_c (sx_c*sw_c) * (qx_c @ qw_c^T), int8-exact path.
// N = K = O = 4096, CHUNKS = 4, cs = 1024.

constexpr int NDIM = 4096;
constexpr int TOTAL4 = (NDIM * NDIM) / 4;   // float4 count per matrix

typedef int i32x4 __attribute__((ext_vector_type(4)));

// ---------------------------------------------------------------- amax pass
__global__ __launch_bounds__(256) void amax_kernel(
    const float* __restrict__ x, const float* __restrict__ w,
    unsigned int* __restrict__ amax) {
  const int t = threadIdx.x;
  const int c = blockIdx.x & 3;  // grid stride (1024*256 float4) is a multiple
                                 // of K/4=1024 -> whole block stays in chunk c
  float mx = 0.f, mw = 0.f;
  const float4* x4 = (const float4*)x;
  const float4* w4 = (const float4*)w;
  const int stride = 1024 * 256;
  for (int i = blockIdx.x * 256 + t; i < TOTAL4; i += stride) {
    float4 v = x4[i];
    mx = fmaxf(mx, fmaxf(fmaxf(fabsf(v.x), fabsf(v.y)),
                         fmaxf(fabsf(v.z), fabsf(v.w))));
    float4 u = w4[i];
    mw = fmaxf(mw, fmaxf(fmaxf(fabsf(u.x), fabsf(u.y)),
                         fmaxf(fabsf(u.z), fabsf(u.w))));
  }
  __shared__ float r0[256], r1[256];
  r0[t] = mx; r1[t] = mw;
  __syncthreads();
  for (int off = 128; off; off >>= 1) {
    if (t < off) {
      r0[t] = fmaxf(r0[t], r0[t + off]);
      r1[t] = fmaxf(r1[t], r1[t + off]);
    }
    __syncthreads();
  }
  if (t == 0) {
    atomicMax(&amax[c],     __float_as_uint(r0[0]));  // non-neg: uint order == float order
    atomicMax(&amax[4 + c], __float_as_uint(r1[0]));
  }
}

// ------------------------------------------------------------- quantize pass
__device__ __forceinline__ signed char quant1(float v, float s) {
  float r = rintf(v / s);                       // round-half-even, IEEE div: matches numpy
  r = fminf(fmaxf(r, -127.f), 127.f);
  return (signed char)(int)r;
}

__global__ __launch_bounds__(256) void quant_kernel(
    const float* __restrict__ x, const float* __restrict__ w,
    const unsigned int* __restrict__ amax,
    signed char* __restrict__ qx, signed char* __restrict__ qw) {
  const int t = threadIdx.x;
  const int c = blockIdx.x & 3;
  const float sx = fmaxf(__uint_as_float(amax[c])     / 127.0f, 1e-8f);
  const float sw = fmaxf(__uint_as_float(amax[4 + c]) / 127.0f, 1e-8f);
  const float4* x4 = (const float4*)x;
  const float4* w4 = (const float4*)w;
  char4* qx4 = (char4*)qx;
  char4* qw4 = (char4*)qw;
  const int stride = 1024 * 256;
  for (int i = blockIdx.x * 256 + t; i < TOTAL4; i += stride) {
    float4 v = x4[i];
    char4 q;
    q.x = quant1(v.x, sx); q.y = quant1(v.y, sx);
    q.z = quant1(v.z, sx); q.w = quant1(v.w, sx);
    qx4[i] = q;
    float4 u = w4[i];
    char4 p;
    p.x = quant1(u.x, sw); p.y = quant1(u.y, sw);
    p.z = quant1(u.z, sw); p.w = quant1(u.w, sw);
    qw4[i] = p;
  }
}

// ------------------------------------------------------------------ i8 GEMM
__device__ __forceinline__ void async16(const void* g, void* l) {
  __builtin_amdgcn_global_load_lds(
      (const __attribute__((address_space(1))) void*)g,
      (__attribute__((address_space(3))) void*)l, 16, 0, 0);
}

// 128x128 tile, BK=64 int8 bytes. 4 waves (2x2), 64x64 out/wave.
// 2-buffer depth-2 pipeline, counted vmcnt + raw s_barrier (R3-proven sync),
// LDS 32 KB + launch_bounds(256,4) -> 4 blocks/CU for cross-block TLP.
// Per K-step t (buf = t&1):
//   vmcnt(4)  -> tile-t loads retired (tile t+1's 4 stay in flight)
//   s_barrier -> all waves' tile-t data visible in LDS
//   COMPUTE   -> 8 ds_read_b128 + 16 mfma_i32_16x16x64_i8 (setprio 1)
//   lgkmcnt(0)-> my reads of buf done
//   s_barrier -> everyone's reads done => safe to re-stage this buf (tile t+2)
// Swizzle (conflict-free, verified): LDS[row][slot] = glob[row][slot^((row>>1)&3)],
// same involution on pre-swizzled global source (linear gload_lds dest) + read addr.
__global__ __launch_bounds__(256, 4) void gemm_i8_kernel(
    const signed char* __restrict__ qx, const signed char* __restrict__ qw,
    const unsigned int* __restrict__ amax, float* __restrict__ out) {
  __shared__ __align__(1024) signed char lds_a[2][8192];
  __shared__ __align__(1024) signed char lds_b[2][8192];

  const int t = threadIdx.x;
  const int lane = t & 63;
  const int wave = t >> 6;
  const int brow = blockIdx.y * 128;   // plain 2D raster (proven L2 locality)
  const int bcol = blockIdx.x * 128;
  const int wr = wave >> 1;
  const int wc = wave & 1;

  // per-chunk combined scales -- loaded and DRAINED before any STAGE so the
  // loop's vmcnt counts see only global_load_lds traffic.
  const float s0 = fmaxf(__uint_as_float(amax[0]) / 127.0f, 1e-8f) *
                   fmaxf(__uint_as_float(amax[4]) / 127.0f, 1e-8f);
  const float s1 = fmaxf(__uint_as_float(amax[1]) / 127.0f, 1e-8f) *
                   fmaxf(__uint_as_float(amax[5]) / 127.0f, 1e-8f);
  const float s2 = fmaxf(__uint_as_float(amax[2]) / 127.0f, 1e-8f) *
                   fmaxf(__uint_as_float(amax[6]) / 127.0f, 1e-8f);
  const float s3 = fmaxf(__uint_as_float(amax[3]) / 127.0f, 1e-8f) *
                   fmaxf(__uint_as_float(amax[7]) / 127.0f, 1e-8f);
  asm volatile("s_waitcnt vmcnt(0)" ::: "memory");
  __builtin_amdgcn_sched_barrier(0);

  // staging addresses: issue i of wave w, lane l -> LDS row ar, 16B slot sl
  const int ar0 = wave * 16 + (lane >> 2);
  const int ar1 = ar0 + 64;
  const int sl = lane & 3;
  const signed char* gax0 = qx + (size_t)(brow + ar0) * NDIM + ((sl ^ ((ar0 >> 1) & 3)) << 4);
  const signed char* gax1 = qx + (size_t)(brow + ar1) * NDIM + ((sl ^ ((ar1 >> 1) & 3)) << 4);
  const signed char* gbx0 = qw + (size_t)(bcol + ar0) * NDIM + ((sl ^ ((ar0 >> 1) & 3)) << 4);
  const signed char* gbx1 = qw + (size_t)(bcol + ar1) * NDIM + ((sl ^ ((ar1 >> 1) & 3)) << 4);
  const int ldsoff = wave * 1024;

  // fragment reads: row = wtile + m*16 + (lane&15), k-slot kg = lane>>4
  const int ra = wr * 64 + (lane & 15);
  const int rb = wc * 64 + (lane & 15);
  const int kg = lane >> 4;
  const int offa = ra * 64 + ((kg ^ ((ra >> 1) & 3)) << 4);
  const int offb = rb * 64 + ((kg ^ ((rb >> 1) & 3)) << 4);

#define STAGE(BUF, T)                                        \
  do {                                                       \
    const int kt_ = (T) * 64;                                \
    async16(gax0 + kt_, &lds_a[BUF][ldsoff]);                \
    async16(gax1 + kt_, &lds_a[BUF][ldsoff + 4096]);         \
    async16(gbx0 + kt_, &lds_b[BUF][ldsoff]);                \
    async16(gbx1 + kt_, &lds_b[BUF][ldsoff + 4096]);         \
  } while (0)

  STAGE(0, 0);
  STAGE(1, 1);

  i32x4 iacc[4][4];
  float facc[4][4][4];
#pragma unroll
  for (int m = 0; m < 4; ++m)
#pragma unroll
    for (int n = 0; n < 4; ++n) {
      iacc[m][n] = i32x4{0, 0, 0, 0};
#pragma unroll
      for (int j = 0; j < 4; ++j) facc[m][n][j] = 0.f;
    }

#define COMPUTE(BUF)                                                    \
  do {                                                                  \
    i32x4 av[4], bv[4];                                                 \
    _Pragma("unroll")                                                   \
    for (int m = 0; m < 4; ++m)                                         \
      av[m] = *(const i32x4*)&lds_a[BUF][offa + m * 1024];              \
    _Pragma("unroll")                                                   \
    for (int n = 0; n < 4; ++n)                                         \
      bv[n] = *(const i32x4*)&lds_b[BUF][offb + n * 1024];              \
    __builtin_amdgcn_s_setprio(1);                                      \
    _Pragma("unroll")                                                   \
    for (int m = 0; m < 4; ++m)                                         \
      _Pragma("unroll")                                                 \
      for (int n = 0; n < 4; ++n)                                       \
        iacc[m][n] = __builtin_amdgcn_mfma_i32_16x16x64_i8(             \
            av[m], bv[n], iacc[m][n], 0, 0, 0);                         \
    __builtin_amdgcn_s_setprio(0);                                      \
  } while (0)

#define FOLD(S)                                                         \
  do {                                                                  \
    _Pragma("unroll")                                                   \
    for (int m = 0; m < 4; ++m)                                         \
      _Pragma("unroll")                                                 \
      for (int n = 0; n < 4; ++n) {                                     \
        _Pragma("unroll")                                               \
        for (int j = 0; j < 4; ++j) facc[m][n][j] += (S) * (float)iacc[m][n][j]; \
        iacc[m][n] = i32x4{0, 0, 0, 0};                                 \
      }                                                                 \
  } while (0)

#define WAITV(N) \
  asm volatile("s_waitcnt vmcnt(" #N ")" ::: "memory"); \
  __builtin_amdgcn_sched_barrier(0)
#define WAITL \
  asm volatile("s_waitcnt lgkmcnt(0)" ::: "memory"); \
  __builtin_amdgcn_sched_barrier(0)
#define BAR \
  __builtin_amdgcn_s_barrier(); \
  __builtin_amdgcn_sched_barrier(0)

#pragma unroll 1
  for (int it = 0; it < 31; ++it) {
    // tile 2it (buf 0)
    WAITV(4); BAR;
    COMPUTE(0);
    WAITL; BAR;
    STAGE(0, 2 * it + 2);
    // tile 2it+1 (buf 1)
    WAITV(4); BAR;
    COMPUTE(1);
    WAITL; BAR;
    STAGE(1, 2 * it + 3);
    if ((it & 7) == 7) {  // tiles (it*2+1)==15,31,47 -> chunk 0,1,2 complete
      const int ci = it >> 3;
      const float sc_ = ci == 0 ? s0 : ci == 1 ? s1 : s2;
      FOLD(sc_);
    }
  }
  // it = 31 peeled: tiles 62, 63; no further staging
  WAITV(4); BAR;
  COMPUTE(0);
  WAITL; BAR;
  WAITV(0); BAR;
  COMPUTE(1);
  FOLD(s3);

  // C/D layout (16x16): col = lane&15, row = (lane>>4)*4 + j
  const int orow = brow + wr * 64 + (lane >> 4) * 4;
  const int ocol = bcol + wc * 64 + (lane & 15);
#pragma unroll
  for (int m = 0; m < 4; ++m)
#pragma unroll
    for (int n = 0; n < 4; ++n)
#pragma unroll
      for (int j = 0; j < 4; ++j)
        out[(size_t)(orow + m * 16 + j) * NDIM + (ocol + n * 16)] = facc[m][n][j];
#undef STAGE
#undef COMPUTE
#undef FOLD
#undef WAITV
#undef WAITL
#undef BAR
}

// ---------------------------------------------------------------- launcher
extern "C" void kernel_launch(void* const* d_in, const int* in_sizes, int n_in,
                              void* d_out, int out_size, void* d_ws, size_t ws_size,
                              hipStream_t stream) {
  const float* x = (const float*)d_in[0];
  const float* w = (const float*)d_in[1];
  float* out = (float*)d_out;

  unsigned int* amax = (unsigned int*)d_ws;                 // 8 uints
  signed char* qx = (signed char*)d_ws + 256;               // 16 MiB
  signed char* qw = qx + (size_t)NDIM * NDIM;               // 16 MiB

  hipMemsetAsync(d_ws, 0, 256, stream);
  amax_kernel<<<1024, 256, 0, stream>>>(x, w, amax);
  quant_kernel<<<1024, 256, 0, stream>>>(x, w, amax, qx, qw);
  dim3 grid(NDIM / 128, NDIM / 128);
  gemm_i8_kernel<<<grid, 256, 0, stream>>>(qx, qw, amax, out);
}

// Round 5
// 197.520 us; speedup vs baseline: 1.0718x; 1.0718x over previous
//
#include <hip/hip_runtime.h>
#include <hip/hip_bf16.h>

// SegmentLinear: y = sum_c (sx_c*sw_c) * (qx_c @ qw_c^T), int8-exact path.
// N = K = O = 4096, CHUNKS = 4, cs = 1024.

constexpr int NDIM = 4096;
constexpr int TOTAL4 = (NDIM * NDIM) / 4;   // float4 count per matrix

typedef int i32x4 __attribute__((ext_vector_type(4)));

// ---------------------------------------------------------------- amax pass
__global__ __launch_bounds__(256) void amax_kernel(
    const float* __restrict__ x, const float* __restrict__ w,
    unsigned int* __restrict__ amax) {
  const int t = threadIdx.x;
  const int c = blockIdx.x & 3;  // grid stride (1024*256 float4) is a multiple
                                 // of K/4=1024 -> whole block stays in chunk c
  float mx = 0.f, mw = 0.f;
  const float4* x4 = (const float4*)x;
  const float4* w4 = (const float4*)w;
  const int stride = 1024 * 256;
  for (int i = blockIdx.x * 256 + t; i < TOTAL4; i += stride) {
    float4 v = x4[i];
    mx = fmaxf(mx, fmaxf(fmaxf(fabsf(v.x), fabsf(v.y)),
                         fmaxf(fabsf(v.z), fabsf(v.w))));
    float4 u = w4[i];
    mw = fmaxf(mw, fmaxf(fmaxf(fabsf(u.x), fabsf(u.y)),
                         fmaxf(fabsf(u.z), fabsf(u.w))));
  }
  __shared__ float r0[256], r1[256];
  r0[t] = mx; r1[t] = mw;
  __syncthreads();
  for (int off = 128; off; off >>= 1) {
    if (t < off) {
      r0[t] = fmaxf(r0[t], r0[t + off]);
      r1[t] = fmaxf(r1[t], r1[t + off]);
    }
    __syncthreads();
  }
  if (t == 0) {
    atomicMax(&amax[c],     __float_as_uint(r0[0]));  // non-neg: uint order == float order
    atomicMax(&amax[4 + c], __float_as_uint(r1[0]));
  }
}

// ------------------------------------------------------------- quantize pass
__device__ __forceinline__ signed char quant1(float v, float s) {
  float r = rintf(v / s);                       // round-half-even, IEEE div: matches numpy
  r = fminf(fmaxf(r, -127.f), 127.f);
  return (signed char)(int)r;
}

__global__ __launch_bounds__(256) void quant_kernel(
    const float* __restrict__ x, const float* __restrict__ w,
    const unsigned int* __restrict__ amax,
    signed char* __restrict__ qx, signed char* __restrict__ qw) {
  const int t = threadIdx.x;
  const int c = blockIdx.x & 3;
  const float sx = fmaxf(__uint_as_float(amax[c])     / 127.0f, 1e-8f);
  const float sw = fmaxf(__uint_as_float(amax[4 + c]) / 127.0f, 1e-8f);
  const float4* x4 = (const float4*)x;
  const float4* w4 = (const float4*)w;
  char4* qx4 = (char4*)qx;
  char4* qw4 = (char4*)qw;
  const int stride = 1024 * 256;
  for (int i = blockIdx.x * 256 + t; i < TOTAL4; i += stride) {
    float4 v = x4[i];
    char4 q;
    q.x = quant1(v.x, sx); q.y = quant1(v.y, sx);
    q.z = quant1(v.z, sx); q.w = quant1(v.w, sx);
    qx4[i] = q;
    float4 u = w4[i];
    char4 p;
    p.x = quant1(u.x, sw); p.y = quant1(u.y, sw);
    p.z = quant1(u.z, sw); p.w = quant1(u.w, sw);
    qw4[i] = p;
  }
}

// ------------------------------------------------------------------ i8 GEMM
__device__ __forceinline__ void async16(const void* g, void* l) {
  __builtin_amdgcn_global_load_lds(
      (const __attribute__((address_space(1))) void*)g,
      (__attribute__((address_space(3))) void*)l, 16, 0, 0);
}

// 128x128 tile, BK=64 int8 bytes. 4 waves (2x2), 64x64 out/wave.
// TRIPLE-buffer depth-3 pipeline (R3-proven vmcnt(8) schedule), 48 KB LDS +
// launch_bounds(256,3) -> 3 blocks/CU, VGPR cap 170 > ~120 needed (no spill;
// R4's (256,4) capped VGPR at 64 and spilled accumulators -> 286 MB scratch).
// buffer(t+3) == buffer(t) mod 3, so each step re-stages the buffer it just
// freed. Per K-step t (buf = t%3):
//   vmcnt(8)  -> tile-t loads retired (tiles t+1,t+2 = 8 loads in flight)
//   s_barrier -> all waves' tile-t data visible in LDS
//   COMPUTE   -> 8 ds_read_b128 + 16 mfma_i32_16x16x64_i8 (setprio 1)
//   lgkmcnt(0)-> my reads of buf done
//   s_barrier -> everyone's reads done => safe to re-stage this buf (tile t+3)
// Swizzle (conflict-free, verified): LDS[row][slot] = glob[row][slot^((row>>1)&3)],
// same involution on pre-swizzled global source (linear gload_lds dest) + read addr.
__global__ __launch_bounds__(256, 3) void gemm_i8_kernel(
    const signed char* __restrict__ qx, const signed char* __restrict__ qw,
    const unsigned int* __restrict__ amax, float* __restrict__ out) {
  __shared__ __align__(1024) signed char lds_a[3][8192];
  __shared__ __align__(1024) signed char lds_b[3][8192];

  const int t = threadIdx.x;
  const int lane = t & 63;
  const int wave = t >> 6;
  const int brow = blockIdx.y * 128;   // plain 2D raster (proven L2 locality)
  const int bcol = blockIdx.x * 128;
  const int wr = wave >> 1;
  const int wc = wave & 1;

  // per-chunk combined scales -- loaded and DRAINED before any STAGE so the
  // loop's vmcnt counts see only global_load_lds traffic.
  const float s0 = fmaxf(__uint_as_float(amax[0]) / 127.0f, 1e-8f) *
                   fmaxf(__uint_as_float(amax[4]) / 127.0f, 1e-8f);
  const float s1 = fmaxf(__uint_as_float(amax[1]) / 127.0f, 1e-8f) *
                   fmaxf(__uint_as_float(amax[5]) / 127.0f, 1e-8f);
  const float s2 = fmaxf(__uint_as_float(amax[2]) / 127.0f, 1e-8f) *
                   fmaxf(__uint_as_float(amax[6]) / 127.0f, 1e-8f);
  const float s3 = fmaxf(__uint_as_float(amax[3]) / 127.0f, 1e-8f) *
                   fmaxf(__uint_as_float(amax[7]) / 127.0f, 1e-8f);
  asm volatile("s_waitcnt vmcnt(0)" ::: "memory");
  __builtin_amdgcn_sched_barrier(0);

  // staging addresses: issue i of wave w, lane l -> LDS row ar, 16B slot sl
  const int ar0 = wave * 16 + (lane >> 2);
  const int ar1 = ar0 + 64;
  const int sl = lane & 3;
  const signed char* gax0 = qx + (size_t)(brow + ar0) * NDIM + ((sl ^ ((ar0 >> 1) & 3)) << 4);
  const signed char* gax1 = qx + (size_t)(brow + ar1) * NDIM + ((sl ^ ((ar1 >> 1) & 3)) << 4);
  const signed char* gbx0 = qw + (size_t)(bcol + ar0) * NDIM + ((sl ^ ((ar0 >> 1) & 3)) << 4);
  const signed char* gbx1 = qw + (size_t)(bcol + ar1) * NDIM + ((sl ^ ((ar1 >> 1) & 3)) << 4);
  const int ldsoff = wave * 1024;

  // fragment reads: row = wtile + m*16 + (lane&15), k-slot kg = lane>>4
  const int ra = wr * 64 + (lane & 15);
  const int rb = wc * 64 + (lane & 15);
  const int kg = lane >> 4;
  const int offa = ra * 64 + ((kg ^ ((ra >> 1) & 3)) << 4);
  const int offb = rb * 64 + ((kg ^ ((rb >> 1) & 3)) << 4);

#define STAGE(BUFOFF, T)                                         \
  do {                                                           \
    const int kt_ = (T) * 64;                                    \
    signed char* la_ = &lds_a[0][0] + (BUFOFF) + ldsoff;         \
    signed char* lb_ = &lds_b[0][0] + (BUFOFF) + ldsoff;         \
    async16(gax0 + kt_, la_);                                    \
    async16(gax1 + kt_, la_ + 4096);                             \
    async16(gbx0 + kt_, lb_);                                    \
    async16(gbx1 + kt_, lb_ + 4096);                             \
  } while (0)

  STAGE(0, 0);
  STAGE(8192, 1);
  STAGE(16384, 2);

  i32x4 iacc[4][4];
  float facc[4][4][4];
#pragma unroll
  for (int m = 0; m < 4; ++m)
#pragma unroll
    for (int n = 0; n < 4; ++n) {
      iacc[m][n] = i32x4{0, 0, 0, 0};
#pragma unroll
      for (int j = 0; j < 4; ++j) facc[m][n][j] = 0.f;
    }

#define COMPUTE(BUFOFF)                                                 \
  do {                                                                  \
    const signed char* la_ = &lds_a[0][0] + (BUFOFF);                   \
    const signed char* lb_ = &lds_b[0][0] + (BUFOFF);                   \
    i32x4 av[4], bv[4];                                                 \
    _Pragma("unroll")                                                   \
    for (int m = 0; m < 4; ++m)                                         \
      av[m] = *(const i32x4*)&la_[offa + m * 1024];                     \
    _Pragma("unroll")                                                   \
    for (int n = 0; n < 4; ++n)                                         \
      bv[n] = *(const i32x4*)&lb_[offb + n * 1024];                     \
    __builtin_amdgcn_s_setprio(1);                                      \
    _Pragma("unroll")                                                   \
    for (int m = 0; m < 4; ++m)                                         \
      _Pragma("unroll")                                                 \
      for (int n = 0; n < 4; ++n)                                       \
        iacc[m][n] = __builtin_amdgcn_mfma_i32_16x16x64_i8(             \
            av[m], bv[n], iacc[m][n], 0, 0, 0);                         \
    __builtin_amdgcn_s_setprio(0);                                      \
  } while (0)

#define FOLD(S)                                                         \
  do {                                                                  \
    _Pragma("unroll")                                                   \
    for (int m = 0; m < 4; ++m)                                         \
      _Pragma("unroll")                                                 \
      for (int n = 0; n < 4; ++n) {                                     \
        _Pragma("unroll")                                               \
        for (int j = 0; j < 4; ++j) facc[m][n][j] += (S) * (float)iacc[m][n][j]; \
        iacc[m][n] = i32x4{0, 0, 0, 0};                                 \
      }                                                                 \
  } while (0)

#define WAITV(N) \
  asm volatile("s_waitcnt vmcnt(" #N ")" ::: "memory"); \
  __builtin_amdgcn_sched_barrier(0)
#define WAITL \
  asm volatile("s_waitcnt lgkmcnt(0)" ::: "memory"); \
  __builtin_amdgcn_sched_barrier(0)
#define BAR \
  __builtin_amdgcn_s_barrier(); \
  __builtin_amdgcn_sched_barrier(0)

  int bufoff = 0;  // (t % 3) * 8192, maintained incrementally
#pragma unroll 1
  for (int tt = 0; tt < 62; ++tt) {
    WAITV(8); BAR;
    COMPUTE(bufoff);
    WAITL; BAR;
    if (tt < 61) STAGE(bufoff, tt + 3);   // re-stage the buffer just freed
    if ((tt & 15) == 15) {                // tt = 15,31,47 -> chunks 0,1,2 done
      const int ci = tt >> 4;
      FOLD(ci == 0 ? s0 : ci == 1 ? s1 : s2);
    }
    bufoff = (bufoff == 16384) ? 0 : bufoff + 8192;
  }
  // tt = 62 (buf 2): only tiles 62,63 outstanding (8 loads)
  WAITV(4); BAR;
  COMPUTE(16384);
  WAITL; BAR;
  // tt = 63 (buf 0)
  WAITV(0); BAR;
  COMPUTE(0);
  FOLD(s3);

  // C/D layout (16x16): col = lane&15, row = (lane>>4)*4 + j
  const int orow = brow + wr * 64 + (lane >> 4) * 4;
  const int ocol = bcol + wc * 64 + (lane & 15);
#pragma unroll
  for (int m = 0; m < 4; ++m)
#pragma unroll
    for (int n = 0; n < 4; ++n)
#pragma unroll
      for (int j = 0; j < 4; ++j)
        out[(size_t)(orow + m * 16 + j) * NDIM + (ocol + n * 16)] = facc[m][n][j];
#undef STAGE
#undef COMPUTE
#undef FOLD
#undef WAITV
#undef WAITL
#undef BAR
}

// ---------------------------------------------------------------- launcher
extern "C" void kernel_launch(void* const* d_in, const int* in_sizes, int n_in,
                              void* d_out, int out_size, void* d_ws, size_t ws_size,
                              hipStream_t stream) {
  const float* x = (const float*)d_in[0];
  const float* w = (const float*)d_in[1];
  float* out = (float*)d_out;

  unsigned int* amax = (unsigned int*)d_ws;                 // 8 uints
  signed char* qx = (signed char*)d_ws + 256;               // 16 MiB
  signed char* qw = qx + (size_t)NDIM * NDIM;               // 16 MiB

  hipMemsetAsync(d_ws, 0, 256, stream);
  amax_kernel<<<1024, 256, 0, stream>>>(x, w, amax);
  quant_kernel<<<1024, 256, 0, stream>>>(x, w, amax, qx, qw);
  dim3 grid(NDIM / 128, NDIM / 128);
  gemm_i8_kernel<<<grid, 256, 0, stream>>>(qx, qw, amax, out);
}

// Round 6
// 163.860 us; speedup vs baseline: 1.2920x; 1.2054x over previous
//
#include <hip/hip_runtime.h>
#include <hip/hip_bf16.h>

// SegmentLinear: y = sum_c (sx_c*sw_c) * (qx_c @ qw_c^T), int8-exact path.
// N = K = O = 4096, CHUNKS = 4, cs = 1024.

constexpr int NDIM = 4096;
constexpr int TOTAL4 = (NDIM * NDIM) / 4;   // float4 count per matrix

typedef int i32x4 __attribute__((ext_vector_type(4)));

// ---------------------------------------------------------------- amax pass
__global__ __launch_bounds__(256) void amax_kernel(
    const float* __restrict__ x, const float* __restrict__ w,
    unsigned int* __restrict__ amax) {
  const int t = threadIdx.x;
  const int c = blockIdx.x & 3;  // grid stride (1024*256 float4) is a multiple
                                 // of K/4=1024 -> whole block stays in chunk c
  float mx = 0.f, mw = 0.f;
  const float4* x4 = (const float4*)x;
  const float4* w4 = (const float4*)w;
  const int stride = 1024 * 256;
  for (int i = blockIdx.x * 256 + t; i < TOTAL4; i += stride) {
    float4 v = x4[i];
    mx = fmaxf(mx, fmaxf(fmaxf(fabsf(v.x), fabsf(v.y)),
                         fmaxf(fabsf(v.z), fabsf(v.w))));
    float4 u = w4[i];
    mw = fmaxf(mw, fmaxf(fmaxf(fabsf(u.x), fabsf(u.y)),
                         fmaxf(fabsf(u.z), fabsf(u.w))));
  }
  __shared__ float r0[256], r1[256];
  r0[t] = mx; r1[t] = mw;
  __syncthreads();
  for (int off = 128; off; off >>= 1) {
    if (t < off) {
      r0[t] = fmaxf(r0[t], r0[t + off]);
      r1[t] = fmaxf(r1[t], r1[t + off]);
    }
    __syncthreads();
  }
  if (t == 0) {
    atomicMax(&amax[c],     __float_as_uint(r0[0]));  // non-neg: uint order == float order
    atomicMax(&amax[4 + c], __float_as_uint(r1[0]));
  }
}

// ------------------------------------------------------------- quantize pass
__device__ __forceinline__ signed char quant1(float v, float s) {
  float r = rintf(v / s);                       // round-half-even, IEEE div: matches numpy
  r = fminf(fmaxf(r, -127.f), 127.f);
  return (signed char)(int)r;
}

__global__ __launch_bounds__(256) void quant_kernel(
    const float* __restrict__ x, const float* __restrict__ w,
    const unsigned int* __restrict__ amax,
    signed char* __restrict__ qx, signed char* __restrict__ qw) {
  const int t = threadIdx.x;
  const int c = blockIdx.x & 3;
  const float sx = fmaxf(__uint_as_float(amax[c])     / 127.0f, 1e-8f);
  const float sw = fmaxf(__uint_as_float(amax[4 + c]) / 127.0f, 1e-8f);
  const float4* x4 = (const float4*)x;
  const float4* w4 = (const float4*)w;
  char4* qx4 = (char4*)qx;
  char4* qw4 = (char4*)qw;
  const int stride = 1024 * 256;
  for (int i = blockIdx.x * 256 + t; i < TOTAL4; i += stride) {
    float4 v = x4[i];
    char4 q;
    q.x = quant1(v.x, sx); q.y = quant1(v.y, sx);
    q.z = quant1(v.z, sx); q.w = quant1(v.w, sx);
    qx4[i] = q;
    float4 u = w4[i];
    char4 p;
    p.x = quant1(u.x, sw); p.y = quant1(u.y, sw);
    p.z = quant1(u.z, sw); p.w = quant1(u.w, sw);
    qw4[i] = p;
  }
}

// ------------------------------------------------------------------ i8 GEMM
__device__ __forceinline__ void async16(const void* g, void* l) {
  __builtin_amdgcn_global_load_lds(
      (const __attribute__((address_space(1))) void*)g,
      (__attribute__((address_space(3))) void*)l, 16, 0, 0);
}

// 128x128 tile, BK=64 int8 bytes. 4 waves (2x2), 64x64 out/wave.
// TRIPLE-buffer depth-3 pipeline (R3-proven vmcnt(8) schedule), 48 KB LDS.
// __launch_bounds__(256, 2): on this compiler arg N targets 2N waves/SIMD,
// so 2 -> VGPR cap 128 (R3: lands at ~116, NO spill). Arg 3/4 capped VGPR at
// 84/64 and spilled the accumulators (R4/R5 regressions). Occupancy is then
// LDS-limited: 160/48 = 3 blocks/CU = 12 waves/CU.
// buffer(t+3) == buffer(t) mod 3, so each step re-stages the buffer it just
// freed. Per K-step t (buf = t%3):
//   vmcnt(8)  -> tile-t loads retired (tiles t+1,t+2 = 8 loads in flight)
//   s_barrier -> all waves' tile-t data visible in LDS
//   COMPUTE   -> 8 ds_read_b128 + 16 mfma_i32_16x16x64_i8 (setprio 1)
//   lgkmcnt(0)-> my reads of buf done
//   s_barrier -> everyone's reads done => safe to re-stage this buf (tile t+3)
// Swizzle (conflict-free, verified): LDS[row][slot] = glob[row][slot^((row>>1)&3)],
// same involution on pre-swizzled global source (linear gload_lds dest) + read addr.
__global__ __launch_bounds__(256, 2) void gemm_i8_kernel(
    const signed char* __restrict__ qx, const signed char* __restrict__ qw,
    const unsigned int* __restrict__ amax, float* __restrict__ out) {
  __shared__ __align__(1024) signed char lds_a[3][8192];
  __shared__ __align__(1024) signed char lds_b[3][8192];

  const int t = threadIdx.x;
  const int lane = t & 63;
  const int wave = t >> 6;
  const int brow = blockIdx.y * 128;   // plain 2D raster (proven L2 locality)
  const int bcol = blockIdx.x * 128;
  const int wr = wave >> 1;
  const int wc = wave & 1;

  // per-chunk combined scales -- loaded and DRAINED before any STAGE so the
  // loop's vmcnt counts see only global_load_lds traffic.
  const float s0 = fmaxf(__uint_as_float(amax[0]) / 127.0f, 1e-8f) *
                   fmaxf(__uint_as_float(amax[4]) / 127.0f, 1e-8f);
  const float s1 = fmaxf(__uint_as_float(amax[1]) / 127.0f, 1e-8f) *
                   fmaxf(__uint_as_float(amax[5]) / 127.0f, 1e-8f);
  const float s2 = fmaxf(__uint_as_float(amax[2]) / 127.0f, 1e-8f) *
                   fmaxf(__uint_as_float(amax[6]) / 127.0f, 1e-8f);
  const float s3 = fmaxf(__uint_as_float(amax[3]) / 127.0f, 1e-8f) *
                   fmaxf(__uint_as_float(amax[7]) / 127.0f, 1e-8f);
  asm volatile("s_waitcnt vmcnt(0)" ::: "memory");
  __builtin_amdgcn_sched_barrier(0);

  // staging addresses: issue i of wave w, lane l -> LDS row ar, 16B slot sl
  const int ar0 = wave * 16 + (lane >> 2);
  const int ar1 = ar0 + 64;
  const int sl = lane & 3;
  const signed char* gax0 = qx + (size_t)(brow + ar0) * NDIM + ((sl ^ ((ar0 >> 1) & 3)) << 4);
  const signed char* gax1 = qx + (size_t)(brow + ar1) * NDIM + ((sl ^ ((ar1 >> 1) & 3)) << 4);
  const signed char* gbx0 = qw + (size_t)(bcol + ar0) * NDIM + ((sl ^ ((ar0 >> 1) & 3)) << 4);
  const signed char* gbx1 = qw + (size_t)(bcol + ar1) * NDIM + ((sl ^ ((ar1 >> 1) & 3)) << 4);
  const int ldsoff = wave * 1024;

  // fragment reads: row = wtile + m*16 + (lane&15), k-slot kg = lane>>4
  const int ra = wr * 64 + (lane & 15);
  const int rb = wc * 64 + (lane & 15);
  const int kg = lane >> 4;
  const int offa = ra * 64 + ((kg ^ ((ra >> 1) & 3)) << 4);
  const int offb = rb * 64 + ((kg ^ ((rb >> 1) & 3)) << 4);

#define STAGE(BUFOFF, T)                                         \
  do {                                                           \
    const int kt_ = (T) * 64;                                    \
    signed char* la_ = &lds_a[0][0] + (BUFOFF) + ldsoff;         \
    signed char* lb_ = &lds_b[0][0] + (BUFOFF) + ldsoff;         \
    async16(gax0 + kt_, la_);                                    \
    async16(gax1 + kt_, la_ + 4096);                             \
    async16(gbx0 + kt_, lb_);                                    \
    async16(gbx1 + kt_, lb_ + 4096);                             \
  } while (0)

  STAGE(0, 0);
  STAGE(8192, 1);
  STAGE(16384, 2);

  i32x4 iacc[4][4];
  float facc[4][4][4];
#pragma unroll
  for (int m = 0; m < 4; ++m)
#pragma unroll
    for (int n = 0; n < 4; ++n) {
      iacc[m][n] = i32x4{0, 0, 0, 0};
#pragma unroll
      for (int j = 0; j < 4; ++j) facc[m][n][j] = 0.f;
    }

#define COMPUTE(BUFOFF)                                                 \
  do {                                                                  \
    const signed char* la_ = &lds_a[0][0] + (BUFOFF);                   \
    const signed char* lb_ = &lds_b[0][0] + (BUFOFF);                   \
    i32x4 av[4], bv[4];                                                 \
    _Pragma("unroll")                                                   \
    for (int m = 0; m < 4; ++m)                                         \
      av[m] = *(const i32x4*)&la_[offa + m * 1024];                     \
    _Pragma("unroll")                                                   \
    for (int n = 0; n < 4; ++n)                                         \
      bv[n] = *(const i32x4*)&lb_[offb + n * 1024];                     \
    __builtin_amdgcn_s_setprio(1);                                      \
    _Pragma("unroll")                                                   \
    for (int m = 0; m < 4; ++m)                                         \
      _Pragma("unroll")                                                 \
      for (int n = 0; n < 4; ++n)                                       \
        iacc[m][n] = __builtin_amdgcn_mfma_i32_16x16x64_i8(             \
            av[m], bv[n], iacc[m][n], 0, 0, 0);                         \
    __builtin_amdgcn_s_setprio(0);                                      \
  } while (0)

#define FOLD(S)                                                         \
  do {                                                                  \
    _Pragma("unroll")                                                   \
    for (int m = 0; m < 4; ++m)                                         \
      _Pragma("unroll")                                                 \
      for (int n = 0; n < 4; ++n) {                                     \
        _Pragma("unroll")                                               \
        for (int j = 0; j < 4; ++j) facc[m][n][j] += (S) * (float)iacc[m][n][j]; \
        iacc[m][n] = i32x4{0, 0, 0, 0};                                 \
      }                                                                 \
  } while (0)

#define WAITV(N) \
  asm volatile("s_waitcnt vmcnt(" #N ")" ::: "memory"); \
  __builtin_amdgcn_sched_barrier(0)
#define WAITL \
  asm volatile("s_waitcnt lgkmcnt(0)" ::: "memory"); \
  __builtin_amdgcn_sched_barrier(0)
#define BAR \
  __builtin_amdgcn_s_barrier(); \
  __builtin_amdgcn_sched_barrier(0)

  int bufoff = 0;  // (t % 3) * 8192, maintained incrementally
#pragma unroll 1
  for (int tt = 0; tt < 62; ++tt) {
    WAITV(8); BAR;
    COMPUTE(bufoff);
    WAITL; BAR;
    if (tt < 61) STAGE(bufoff, tt + 3);   // re-stage the buffer just freed
    if ((tt & 15) == 15) {                // tt = 15,31,47 -> chunks 0,1,2 done
      const int ci = tt >> 4;
      FOLD(ci == 0 ? s0 : ci == 1 ? s1 : s2);
    }
    bufoff = (bufoff == 16384) ? 0 : bufoff + 8192;
  }
  // tt = 62 (buf 2): only tiles 62,63 outstanding (8 loads)
  WAITV(4); BAR;
  COMPUTE(16384);
  WAITL; BAR;
  // tt = 63 (buf 0)
  WAITV(0); BAR;
  COMPUTE(0);
  FOLD(s3);

  // C/D layout (16x16): col = lane&15, row = (lane>>4)*4 + j
  const int orow = brow + wr * 64 + (lane >> 4) * 4;
  const int ocol = bcol + wc * 64 + (lane & 15);
#pragma unroll
  for (int m = 0; m < 4; ++m)
#pragma unroll
    for (int n = 0; n < 4; ++n)
#pragma unroll
      for (int j = 0; j < 4; ++j)
        out[(size_t)(orow + m * 16 + j) * NDIM + (ocol + n * 16)] = facc[m][n][j];
#undef STAGE
#undef COMPUTE
#undef FOLD
#undef WAITV
#undef WAITL
#undef BAR
}

// ---------------------------------------------------------------- launcher
extern "C" void kernel_launch(void* const* d_in, const int* in_sizes, int n_in,
                              void* d_out, int out_size, void* d_ws, size_t ws_size,
                              hipStream_t stream) {
  const float* x = (const float*)d_in[0];
  const float* w = (const float*)d_in[1];
  float* out = (float*)d_out;

  unsigned int* amax = (unsigned int*)d_ws;                 // 8 uints
  signed char* qx = (signed char*)d_ws + 256;               // 16 MiB
  signed char* qw = qx + (size_t)NDIM * NDIM;               // 16 MiB

  hipMemsetAsync(d_ws, 0, 256, stream);
  amax_kernel<<<1024, 256, 0, stream>>>(x, w, amax);
  quant_kernel<<<1024, 256, 0, stream>>>(x, w, amax, qx, qw);
  dim3 grid(NDIM / 128, NDIM / 128);
  gemm_i8_kernel<<<grid, 256, 0, stream>>>(qx, qw, amax, out);
}

// Round 7
// 145.207 us; speedup vs baseline: 1.4580x; 1.1285x over previous
//
#include <hip/hip_runtime.h>
#include <hip/hip_bf16.h>

// SegmentLinear: y = sum_c (sx_c*sw_c) * (qx_c @ qw_c^T), int8-exact path.
// N = K = O = 4096, CHUNKS = 4, cs = 1024.

constexpr int NDIM = 4096;
constexpr int TOTAL4 = (NDIM * NDIM) / 4;   // float4 count per matrix

typedef int i32x4 __attribute__((ext_vector_type(4)));

// ---------------------------------------------------------------- amax pass
__global__ __launch_bounds__(256) void amax_kernel(
    const float* __restrict__ x, const float* __restrict__ w,
    unsigned int* __restrict__ amax) {
  const int t = threadIdx.x;
  const int c = blockIdx.x & 3;  // grid stride (1024*256 float4) is a multiple
                                 // of K/4=1024 -> whole block stays in chunk c
  float mx = 0.f, mw = 0.f;
  const float4* x4 = (const float4*)x;
  const float4* w4 = (const float4*)w;
  const int stride = 1024 * 256;
  for (int i = blockIdx.x * 256 + t; i < TOTAL4; i += stride) {
    float4 v = x4[i];
    mx = fmaxf(mx, fmaxf(fmaxf(fabsf(v.x), fabsf(v.y)),
                         fmaxf(fabsf(v.z), fabsf(v.w))));
    float4 u = w4[i];
    mw = fmaxf(mw, fmaxf(fmaxf(fabsf(u.x), fabsf(u.y)),
                         fmaxf(fabsf(u.z), fabsf(u.w))));
  }
  __shared__ float r0[256], r1[256];
  r0[t] = mx; r1[t] = mw;
  __syncthreads();
  for (int off = 128; off; off >>= 1) {
    if (t < off) {
      r0[t] = fmaxf(r0[t], r0[t + off]);
      r1[t] = fmaxf(r1[t], r1[t + off]);
    }
    __syncthreads();
  }
  if (t == 0) {
    atomicMax(&amax[c],     __float_as_uint(r0[0]));  // non-neg: uint order == float order
    atomicMax(&amax[4 + c], __float_as_uint(r1[0]));
  }
}

// ------------------------------------------------------------- quantize pass
__device__ __forceinline__ signed char quant1(float v, float s) {
  float r = rintf(v / s);                       // round-half-even, IEEE div: matches numpy
  r = fminf(fmaxf(r, -127.f), 127.f);
  return (signed char)(int)r;
}

__global__ __launch_bounds__(256) void quant_kernel(
    const float* __restrict__ x, const float* __restrict__ w,
    const unsigned int* __restrict__ amax,
    signed char* __restrict__ qx, signed char* __restrict__ qw) {
  const int t = threadIdx.x;
  const int c = blockIdx.x & 3;
  const float sx = fmaxf(__uint_as_float(amax[c])     / 127.0f, 1e-8f);
  const float sw = fmaxf(__uint_as_float(amax[4 + c]) / 127.0f, 1e-8f);
  const float4* x4 = (const float4*)x;
  const float4* w4 = (const float4*)w;
  char4* qx4 = (char4*)qx;
  char4* qw4 = (char4*)qw;
  const int stride = 1024 * 256;
  for (int i = blockIdx.x * 256 + t; i < TOTAL4; i += stride) {
    float4 v = x4[i];
    char4 q;
    q.x = quant1(v.x, sx); q.y = quant1(v.y, sx);
    q.z = quant1(v.z, sx); q.w = quant1(v.w, sx);
    qx4[i] = q;
    float4 u = w4[i];
    char4 p;
    p.x = quant1(u.x, sw); p.y = quant1(u.y, sw);
    p.z = quant1(u.z, sw); p.w = quant1(u.w, sw);
    qw4[i] = p;
  }
}

// ------------------------------------------------------------------ i8 GEMM
__device__ __forceinline__ void async16(const void* g, void* l) {
  __builtin_amdgcn_global_load_lds(
      (const __attribute__((address_space(1))) void*)g,
      (__attribute__((address_space(3))) void*)l, 16, 0, 0);
}

// 128x128 tile, BK=128 int8 bytes (double R3's K-step: 32 MFMA + 16 ds_read
// per barrier pair instead of 16+8 -> half the sync overhead). 4 waves (2x2),
// 64x64 out/wave, 2 static buffers (64 KB LDS), unroll-by-2 loop with
// compile-time buffer offsets (R3-proven codegen; runtime offsets in R6
// degraded regalloc). launch_bounds(256,2): VGPR cap 128, no spill (R3).
// Sync per K-step t (R3-proven ledger, 8 loads/stage):
//   vmcnt(8)  -> tile-t loads retired (tile t+1's 8 stay in flight)
//   s_barrier -> all waves' tile-t data visible in LDS
//   COMPUTE   -> 16 ds_read_b128 + 32 mfma_i32_16x16x64_i8 (setprio 1)
//   lgkmcnt(0)-> my reads of this buf done
//   s_barrier -> everyone's reads done => safe to re-stage this buf (tile t+2)
// Swizzle for 128B rows (bank = fn(col) only): slot' = slot ^ (row&7) over
// eight 16B slots -> 16-lane kg-group covers all 32 banks, max 2-way (free).
// Same involution pre-applied to the global source (linear gload_lds dest);
// row&7 == (t>>3)&7 for every 32-row issue block, so one swizzled base
// pointer per matrix serves all 4 issues.
__global__ __launch_bounds__(256, 2) void gemm_i8_kernel(
    const signed char* __restrict__ qx, const signed char* __restrict__ qw,
    const unsigned int* __restrict__ amax, float* __restrict__ out) {
  __shared__ __align__(1024) signed char lds_a[2][16384];
  __shared__ __align__(1024) signed char lds_b[2][16384];

  const int t = threadIdx.x;
  const int lane = t & 63;
  const int wave = t >> 6;
  const int brow = blockIdx.y * 128;   // plain 2D raster (proven L2 locality)
  const int bcol = blockIdx.x * 128;
  const int wr = wave >> 1;
  const int wc = wave & 1;

  // per-chunk combined scales -- loaded and DRAINED before any STAGE so the
  // loop's vmcnt counts see only global_load_lds traffic.
  const float s0 = fmaxf(__uint_as_float(amax[0]) / 127.0f, 1e-8f) *
                   fmaxf(__uint_as_float(amax[4]) / 127.0f, 1e-8f);
  const float s1 = fmaxf(__uint_as_float(amax[1]) / 127.0f, 1e-8f) *
                   fmaxf(__uint_as_float(amax[5]) / 127.0f, 1e-8f);
  const float s2 = fmaxf(__uint_as_float(amax[2]) / 127.0f, 1e-8f) *
                   fmaxf(__uint_as_float(amax[6]) / 127.0f, 1e-8f);
  const float s3 = fmaxf(__uint_as_float(amax[3]) / 127.0f, 1e-8f) *
                   fmaxf(__uint_as_float(amax[7]) / 127.0f, 1e-8f);
  asm volatile("s_waitcnt vmcnt(0)" ::: "memory");
  __builtin_amdgcn_sched_barrier(0);

  // staging: issue j (j=0..3 per matrix) writes LDS bytes [j*4096 + t*16]
  //   -> LDS row = j*32 + (t>>3), 16B slot = t&7 (linear dest).
  // Global col pre-swizzled: (t&7) ^ ((t>>3)&7) == slot ^ (row&7) for all j.
  const int srow = t >> 3;                                  // 0..31
  const int scol = (((t & 7) ^ (srow & 7)) << 4);           // swizzled byte col
  const signed char* gA = qx + (size_t)(brow + srow) * NDIM + scol;
  const signed char* gB = qw + (size_t)(bcol + srow) * NDIM + scol;
  signed char* laW = &lds_a[0][0] + wave * 1024;            // wave-uniform base
  signed char* lbW = &lds_b[0][0] + wave * 1024;

  // fragment reads: A row = wr*64 + m*16 + (lane&15); row&7 == lane&7.
  // k byte-slot for half ks, group kg: slot = (ks*4+kg) ^ (lane&7).
  const int kg = lane >> 4;
  const int l7 = lane & 7;
  const int sk0 = ((kg) ^ l7) << 4;
  const int sk1 = ((4 + kg) ^ l7) << 4;
  const int rba = (wr * 64 + (lane & 15)) * 128;   // + m*2048
  const int rbb = (wc * 64 + (lane & 15)) * 128;   // + n*2048

#define STAGE(BUFOFF, T)                                              \
  do {                                                                \
    const size_t kt_ = (size_t)(T) * 128;                             \
    async16(gA + kt_,                  laW + (BUFOFF));               \
    async16(gA + kt_ + 32u * NDIM,     laW + (BUFOFF) + 4096);        \
    async16(gA + kt_ + 64u * NDIM,     laW + (BUFOFF) + 8192);        \
    async16(gA + kt_ + 96u * NDIM,     laW + (BUFOFF) + 12288);       \
    async16(gB + kt_,                  lbW + (BUFOFF));               \
    async16(gB + kt_ + 32u * NDIM,     lbW + (BUFOFF) + 4096);        \
    async16(gB + kt_ + 64u * NDIM,     lbW + (BUFOFF) + 8192);        \
    async16(gB + kt_ + 96u * NDIM,     lbW + (BUFOFF) + 12288);       \
  } while (0)

  STAGE(0, 0);
  STAGE(16384, 1);

  i32x4 iacc[4][4];
  float facc[4][4][4];
#pragma unroll
  for (int m = 0; m < 4; ++m)
#pragma unroll
    for (int n = 0; n < 4; ++n) {
      iacc[m][n] = i32x4{0, 0, 0, 0};
#pragma unroll
      for (int j = 0; j < 4; ++j) facc[m][n][j] = 0.f;
    }

#define HALF(LA, LB, SK)                                                \
  do {                                                                  \
    i32x4 av[4], bv[4];                                                 \
    _Pragma("unroll")                                                   \
    for (int m = 0; m < 4; ++m)                                         \
      av[m] = *(const i32x4*)&(LA)[rba + m * 2048 + (SK)];              \
    _Pragma("unroll")                                                   \
    for (int n = 0; n < 4; ++n)                                         \
      bv[n] = *(const i32x4*)&(LB)[rbb + n * 2048 + (SK)];              \
    __builtin_amdgcn_s_setprio(1);                                      \
    _Pragma("unroll")                                                   \
    for (int m = 0; m < 4; ++m)                                         \
      _Pragma("unroll")                                                 \
      for (int n = 0; n < 4; ++n)                                       \
        iacc[m][n] = __builtin_amdgcn_mfma_i32_16x16x64_i8(             \
            av[m], bv[n], iacc[m][n], 0, 0, 0);                         \
    __builtin_amdgcn_s_setprio(0);                                      \
  } while (0)

#define COMPUTE(BUFOFF)                                                 \
  do {                                                                  \
    const signed char* la_ = &lds_a[0][0] + (BUFOFF);                   \
    const signed char* lb_ = &lds_b[0][0] + (BUFOFF);                   \
    HALF(la_, lb_, sk0);                                                \
    HALF(la_, lb_, sk1);                                                \
  } while (0)

#define FOLD(S)                                                         \
  do {                                                                  \
    _Pragma("unroll")                                                   \
    for (int m = 0; m < 4; ++m)                                         \
      _Pragma("unroll")                                                 \
      for (int n = 0; n < 4; ++n) {                                     \
        _Pragma("unroll")                                               \
        for (int j = 0; j < 4; ++j) facc[m][n][j] += (S) * (float)iacc[m][n][j]; \
        iacc[m][n] = i32x4{0, 0, 0, 0};                                 \
      }                                                                 \
  } while (0)

#define WAITV(N) \
  asm volatile("s_waitcnt vmcnt(" #N ")" ::: "memory"); \
  __builtin_amdgcn_sched_barrier(0)
#define WAITL \
  asm volatile("s_waitcnt lgkmcnt(0)" ::: "memory"); \
  __builtin_amdgcn_sched_barrier(0)
#define BAR \
  __builtin_amdgcn_s_barrier(); \
  __builtin_amdgcn_sched_barrier(0)

  // 32 K-tiles of 128 bytes; chunk c = tiles 8c..8c+7.
#pragma unroll 1
  for (int it = 0; it < 15; ++it) {
    // tile 2it (buf 0)
    WAITV(8); BAR;
    COMPUTE(0);
    WAITL; BAR;
    STAGE(0, 2 * it + 2);
    // tile 2it+1 (buf 1)
    WAITV(8); BAR;
    COMPUTE(16384);
    WAITL; BAR;
    STAGE(16384, 2 * it + 3);
    if ((it & 3) == 3) {            // after tiles 7,15,23 -> chunks 0,1,2 done
      const int ci = it >> 2;
      FOLD(ci == 0 ? s0 : ci == 1 ? s1 : s2);
    }
  }
  // peel: tiles 30 (buf 0), 31 (buf 1); 16 loads outstanding here
  WAITV(8); BAR;
  COMPUTE(0);
  WAITL; BAR;
  WAITV(0); BAR;
  COMPUTE(16384);
  FOLD(s3);

  // C/D layout (16x16): col = lane&15, row = (lane>>4)*4 + j
  const int orow = brow + wr * 64 + (lane >> 4) * 4;
  const int ocol = bcol + wc * 64 + (lane & 15);
#pragma unroll
  for (int m = 0; m < 4; ++m)
#pragma unroll
    for (int n = 0; n < 4; ++n)
#pragma unroll
      for (int j = 0; j < 4; ++j)
        out[(size_t)(orow + m * 16 + j) * NDIM + (ocol + n * 16)] = facc[m][n][j];
#undef STAGE
#undef HALF
#undef COMPUTE
#undef FOLD
#undef WAITV
#undef WAITL
#undef BAR
}

// ---------------------------------------------------------------- launcher
extern "C" void kernel_launch(void* const* d_in, const int* in_sizes, int n_in,
                              void* d_out, int out_size, void* d_ws, size_t ws_size,
                              hipStream_t stream) {
  const float* x = (const float*)d_in[0];
  const float* w = (const float*)d_in[1];
  float* out = (float*)d_out;

  unsigned int* amax = (unsigned int*)d_ws;                 // 8 uints
  signed char* qx = (signed char*)d_ws + 256;               // 16 MiB
  signed char* qw = qx + (size_t)NDIM * NDIM;               // 16 MiB

  hipMemsetAsync(d_ws, 0, 256, stream);
  amax_kernel<<<1024, 256, 0, stream>>>(x, w, amax);
  quant_kernel<<<1024, 256, 0, stream>>>(x, w, amax, qx, qw);
  dim3 grid(NDIM / 128, NDIM / 128);
  gemm_i8_kernel<<<grid, 256, 0, stream>>>(qx, qw, amax, out);
}